// Round 3
// baseline (47.918 us; speedup 1.0000x reference)
//
#include <hip/hip_runtime.h>
#include <hip/hip_cooperative_groups.h>
#include <math.h>

namespace cg = cooperative_groups;

#define HDIM 1024
#define BATCH 8
#define SEQ 4096

// d_ws layout (u64 units):
//   [0, 16K)        wsgn_t[16][1024]  bit l of word (w=k*4+j, o): W[o][k*256+l*4+j] < 0
//   [16K, 32K)      wnz_t [16][1024]  same mapping, value != 0
//   [32K, 32K+128)  xsgn[8][16]
//   [32K+128, +256) xnz [8][16]
//   then (as float*) wpart[256]  per-block partial sum|W|
#define U64_WSGN 0
#define U64_WNZ  (16 * 1024)
#define U64_XSGN (32 * 1024)
#define U64_XNZ  (32 * 1024 + 128)
#define U64_TOT  (32 * 1024 + 256)

__global__ __launch_bounds__(256) void k_fused(const float* __restrict__ hs,
                                               const float* __restrict__ W,
                                               const float* __restrict__ bias,
                                               const float* __restrict__ alpha,
                                               float* __restrict__ out,
                                               unsigned long long* __restrict__ ws64,
                                               float* __restrict__ wpart) {
    __shared__ float swabs[4];
    __shared__ float red[256];
    __shared__ unsigned long long lxs[128];  // xsgn[b*16+w]
    __shared__ unsigned long long lxn[128];  // xnz [b*16+w]

    const int tid = threadIdx.x;
    const int wave = tid >> 6, lane = tid & 63;
    const int g = blockIdx.x * 4 + wave;     // W row owned by this wave (0..1023)

    // ---------------- phase 1: masks + |W| partials ----------------
    {
        const float* row = W + (size_t)g * HDIM;
        float aabs = 0.f;
        #pragma unroll
        for (int k = 0; k < 4; ++k) {
            float4 v = *reinterpret_cast<const float4*>(row + k * 256 + lane * 4);
            const float ee[4] = {v.x, v.y, v.z, v.w};
            #pragma unroll
            for (int j = 0; j < 4; ++j) {
                unsigned long long sg = __ballot(ee[j] < 0.f);
                unsigned long long nz = __ballot(ee[j] != 0.f);
                const int w = k * 4 + j;
                if (lane == 0) {
                    ws64[U64_WSGN + w * 1024 + g] = sg;
                    ws64[U64_WNZ  + w * 1024 + g] = nz;
                }
                aabs += fabsf(ee[j]);
            }
        }
        #pragma unroll
        for (int off = 32; off >= 1; off >>= 1) aabs += __shfl_down(aabs, off, 64);
        if (lane == 0) swabs[wave] = aabs;

        if (g < BATCH) {  // waves 0..7 (blocks 0,1) also ballot the first-token rows
            const float* xr = hs + (size_t)g * SEQ * HDIM;
            #pragma unroll
            for (int k = 0; k < 4; ++k) {
                float4 v = *reinterpret_cast<const float4*>(xr + k * 256 + lane * 4);
                const float ee[4] = {v.x, v.y, v.z, v.w};
                #pragma unroll
                for (int j = 0; j < 4; ++j) {
                    unsigned long long sg = __ballot(ee[j] < 0.f);
                    unsigned long long nz = __ballot(ee[j] != 0.f);
                    const int w = k * 4 + j;
                    if (lane == 0) {
                        ws64[U64_XSGN + g * 16 + w] = sg;
                        ws64[U64_XNZ  + g * 16 + w] = nz;
                    }
                }
            }
        }
    }
    __syncthreads();
    if (tid == 0) wpart[blockIdx.x] = swabs[0] + swabs[1] + swabs[2] + swabs[3];

    cg::this_grid().sync();

    // ---------------- phase 2: popcount dot + tanh ----------------
    // preload x masks + reduce wpart
    if (tid < 128)      lxs[tid] = ws64[U64_XSGN + tid];
    else                lxn[tid - 128] = ws64[U64_XNZ + (tid - 128)];
    red[tid] = wpart[tid];
    __syncthreads();
    #pragma unroll
    for (int off = 128; off >= 1; off >>= 1) {
        if (tid < off) red[tid] += red[tid + off];
        __syncthreads();
    }
    float a = alpha[0];
    if (a < 1e-5f) a = 1e-5f;
    const float scale = a * red[0] * (1.0f / 1048576.0f);

    // wave `wave` handles output column o = g for all 8 batches; 8 lanes/output
    const int o = g;                 // 0..1023
    const int b = lane >> 3;         // 0..7
    const int sub = lane & 7;        // 0..7 -> words 2*sub, 2*sub+1
    const int w0 = 2 * sub, w1 = 2 * sub + 1;

    unsigned long long wsg0 = ws64[U64_WSGN + w0 * 1024 + o];
    unsigned long long wnz0 = ws64[U64_WNZ  + w0 * 1024 + o];
    unsigned long long wsg1 = ws64[U64_WSGN + w1 * 1024 + o];
    unsigned long long wnz1 = ws64[U64_WNZ  + w1 * 1024 + o];

    unsigned long long u0 = wnz0 & lxn[b * 16 + w0];
    unsigned long long m0 = (wsg0 ^ lxs[b * 16 + w0]) & u0;
    unsigned long long u1 = wnz1 & lxn[b * 16 + w1];
    unsigned long long m1 = (wsg1 ^ lxs[b * 16 + w1]) & u1;

    int n = __popcll(u0) + __popcll(u1);
    int d = __popcll(m0) + __popcll(m1);
    #pragma unroll
    for (int s = 1; s < 8; s <<= 1) {
        n += __shfl_xor(n, s, 8);
        d += __shfl_xor(d, s, 8);
    }
    if (sub == 0) {
        out[b * HDIM + o] = tanhf(scale * (float)(n - 2 * d) + bias[o]);
    }
}

extern "C" void kernel_launch(void* const* d_in, const int* in_sizes, int n_in,
                              void* d_out, int out_size, void* d_ws, size_t ws_size,
                              hipStream_t stream) {
    const float* hs    = (const float*)d_in[0];
    const float* W     = (const float*)d_in[1];
    const float* bias  = (const float*)d_in[2];
    const float* alpha = (const float*)d_in[3];
    float* out = (float*)d_out;

    unsigned long long* ws64 = (unsigned long long*)d_ws;
    float* wpart = (float*)(ws64 + U64_TOT);

    void* args[] = {(void*)&hs, (void*)&W, (void*)&bias, (void*)&alpha,
                    (void*)&out, (void*)&ws64, (void*)&wpart};
    hipLaunchCooperativeKernel(reinterpret_cast<void*>(k_fused),
                               dim3(256), dim3(256), args, 0, stream);
}

// Round 4
// 32.679 us; speedup vs baseline: 1.4663x; 1.4663x over previous
//
#include <hip/hip_runtime.h>
#include <math.h>

#define HDIM 1024
#define BATCH 8
#define SEQ 4096
#define FLAG_TAG 0x5A5A5A5Au

// d_ws layout: u32 flags[256] | f32 wpart[256] | i32 dot[8][1024]

__global__ __launch_bounds__(256) void k_fused(const float* __restrict__ hs,
                                               const float* __restrict__ W,
                                               const float* __restrict__ bias,
                                               const float* __restrict__ alpha,
                                               float* __restrict__ out,
                                               unsigned int* __restrict__ flags,
                                               float* __restrict__ wpart,
                                               int* __restrict__ dot) {
    __shared__ float swabs[4];
    __shared__ float red[256];
    const int tid = threadIdx.x;
    const int wave = tid >> 6, lane = tid & 63;
    const int o = blockIdx.x * 4 + wave;          // W row owned by this wave

    // ---------------- phase 1: exact sign-dot + |W| partial ----------------
    const float* wrow = W + (size_t)o * HDIM;
    float aabs = 0.f;
    int n[BATCH], d[BATCH];
    #pragma unroll
    for (int b = 0; b < BATCH; ++b) { n[b] = 0; d[b] = 0; }

    #pragma unroll
    for (int k = 0; k < 4; ++k) {
        const int h0 = k * 256 + lane * 4;
        float4 wv = *reinterpret_cast<const float4*>(wrow + h0);
        const float we[4] = {wv.x, wv.y, wv.z, wv.w};
        float xe[BATCH][4];
        #pragma unroll
        for (int b = 0; b < BATCH; ++b) {
            float4 xv = *reinterpret_cast<const float4*>(hs + (size_t)b * SEQ * HDIM + h0);
            xe[b][0] = xv.x; xe[b][1] = xv.y; xe[b][2] = xv.z; xe[b][3] = xv.w;
        }
        #pragma unroll
        for (int j = 0; j < 4; ++j) {
            unsigned long long wsg = __ballot(we[j] < 0.f);
            unsigned long long wnz = __ballot(we[j] != 0.f);
            aabs += fabsf(we[j]);
            #pragma unroll
            for (int b = 0; b < BATCH; ++b) {
                unsigned long long u = wnz & __ballot(xe[b][j] != 0.f);
                unsigned long long m = (wsg ^ __ballot(xe[b][j] < 0.f)) & u;
                n[b] += __popcll(u);
                d[b] += __popcll(m);
            }
        }
    }

    #pragma unroll
    for (int off = 32; off >= 1; off >>= 1) aabs += __shfl_down(aabs, off, 64);
    if (lane == 0) {
        swabs[wave] = aabs;
        #pragma unroll
        for (int b = 0; b < BATCH; ++b) dot[b * HDIM + o] = n[b] - 2 * d[b];
    }
    __syncthreads();
    if (tid == 0) {
        wpart[blockIdx.x] = swabs[0] + swabs[1] + swabs[2] + swabs[3];
        __threadfence();   // drain data stores to device scope
        __hip_atomic_store(&flags[blockIdx.x], FLAG_TAG,
                           __ATOMIC_RELEASE, __HIP_MEMORY_SCOPE_AGENT);
    }
    if (blockIdx.x != 0) return;

    // ---------------- phase 2: block 0 finishes ----------------
    while (__hip_atomic_load(&flags[tid], __ATOMIC_ACQUIRE,
                             __HIP_MEMORY_SCOPE_AGENT) != FLAG_TAG)
        __builtin_amdgcn_s_sleep(2);
    __threadfence();
    red[tid] = wpart[tid];
    __syncthreads();
    #pragma unroll
    for (int off = 128; off >= 1; off >>= 1) {
        if (tid < off) red[tid] += red[tid + off];
        __syncthreads();
    }
    float a = alpha[0];
    if (a < 1e-5f) a = 1e-5f;
    const float scale = a * red[0] * (1.0f / 1048576.0f);

    const float4 bv = *reinterpret_cast<const float4*>(bias + tid * 4);
    #pragma unroll
    for (int b = 0; b < BATCH; ++b) {
        int4 dv = *reinterpret_cast<const int4*>(dot + b * HDIM + tid * 4);
        float4 r;
        r.x = tanhf(scale * (float)dv.x + bv.x);
        r.y = tanhf(scale * (float)dv.y + bv.y);
        r.z = tanhf(scale * (float)dv.z + bv.z);
        r.w = tanhf(scale * (float)dv.w + bv.w);
        *reinterpret_cast<float4*>(out + b * HDIM + tid * 4) = r;
    }
    // reset flags so the next (replayed) call starts clean
    __hip_atomic_store(&flags[tid], 0u, __ATOMIC_RELAXED, __HIP_MEMORY_SCOPE_AGENT);
}

extern "C" void kernel_launch(void* const* d_in, const int* in_sizes, int n_in,
                              void* d_out, int out_size, void* d_ws, size_t ws_size,
                              hipStream_t stream) {
    const float* hs    = (const float*)d_in[0];
    const float* W     = (const float*)d_in[1];
    const float* bias  = (const float*)d_in[2];
    const float* alpha = (const float*)d_in[3];
    float* out = (float*)d_out;

    unsigned int* flags = (unsigned int*)d_ws;
    float* wpart = (float*)(flags + 256);
    int* dot = (int*)(wpart + 256);

    k_fused<<<256, 256, 0, stream>>>(hs, W, bias, alpha, out, flags, wpart, dot);
}

// Round 6
// 12.052 us; speedup vs baseline: 3.9759x; 2.7115x over previous
//
#include <hip/hip_runtime.h>
#include <math.h>

#define HDIM 1024
#define BATCH 8
#define SEQ 4096

// d_ws layout: f32 wpart[4096] | i32 dotp[4][8][1024]

__global__ __launch_bounds__(256) void k1(const float* __restrict__ hs,
                                          const float* __restrict__ W,
                                          float* __restrict__ wpart,
                                          int* __restrict__ dotp) {
    const int tid = threadIdx.x;
    const int wave = tid >> 6, lane = tid & 63;
    const int gw = blockIdx.x * 4 + wave;   // 0..4095
    const int o = gw & (HDIM - 1);          // output row
    const int part = gw >> 10;              // 0..3 quarter of the H dim
    const int h0 = part * 256 + lane * 4;

    float4 wv = *reinterpret_cast<const float4*>(W + (size_t)o * HDIM + h0);
    const float we[4] = {wv.x, wv.y, wv.z, wv.w};

    float xe[BATCH][4];
    #pragma unroll
    for (int b = 0; b < BATCH; ++b) {
        float4 xv = *reinterpret_cast<const float4*>(hs + (size_t)b * SEQ * HDIM + h0);
        xe[b][0] = xv.x; xe[b][1] = xv.y; xe[b][2] = xv.z; xe[b][3] = xv.w;
    }

    float aabs = 0.f;
    int n[BATCH], d[BATCH];
    #pragma unroll
    for (int b = 0; b < BATCH; ++b) { n[b] = 0; d[b] = 0; }

    #pragma unroll
    for (int j = 0; j < 4; ++j) {
        unsigned long long wsg = __ballot(we[j] < 0.f);
        unsigned long long wnz = __ballot(we[j] != 0.f);
        aabs += fabsf(we[j]);
        #pragma unroll
        for (int b = 0; b < BATCH; ++b) {
            unsigned long long u = wnz & __ballot(xe[b][j] != 0.f);
            unsigned long long m = (wsg ^ __ballot(xe[b][j] < 0.f)) & u;
            n[b] += __popcll(u);
            d[b] += __popcll(m);
        }
    }

    #pragma unroll
    for (int off = 32; off >= 1; off >>= 1) aabs += __shfl_down(aabs, off, 64);
    if (lane == 0) {
        wpart[gw] = aabs;
        #pragma unroll
        for (int b = 0; b < BATCH; ++b)
            dotp[(part * BATCH + b) * HDIM + o] = n[b] - 2 * d[b];
    }
}

__global__ __launch_bounds__(256) void k2(const int* __restrict__ dotp,
                                          const float* __restrict__ wpart,
                                          const float* __restrict__ bias,
                                          const float* __restrict__ alpha,
                                          float* __restrict__ out) {
    __shared__ float red[256];
    const int tid = threadIdx.x;
    float s = 0.f;
    #pragma unroll
    for (int i = 0; i < 16; ++i) s += wpart[tid + i * 256];
    red[tid] = s;
    __syncthreads();
    #pragma unroll
    for (int off = 128; off >= 1; off >>= 1) {
        if (tid < off) red[tid] += red[tid + off];
        __syncthreads();
    }
    float a = alpha[0];
    if (a < 1e-5f) a = 1e-5f;
    const float scale = a * red[0] * (1.0f / 1048576.0f);

    const int idx = blockIdx.x * 256 + tid;   // b*1024 + o
    const int b = idx >> 10, o = idx & (HDIM - 1);
    int dsum = dotp[(0 * BATCH + b) * HDIM + o]
             + dotp[(1 * BATCH + b) * HDIM + o]
             + dotp[(2 * BATCH + b) * HDIM + o]
             + dotp[(3 * BATCH + b) * HDIM + o];
    out[idx] = tanhf(scale * (float)dsum + bias[o]);
}

extern "C" void kernel_launch(void* const* d_in, const int* in_sizes, int n_in,
                              void* d_out, int out_size, void* d_ws, size_t ws_size,
                              hipStream_t stream) {
    const float* hs    = (const float*)d_in[0];
    const float* W     = (const float*)d_in[1];
    const float* bias  = (const float*)d_in[2];
    const float* alpha = (const float*)d_in[3];
    float* out = (float*)d_out;

    float* wpart = (float*)d_ws;                 // 4096 floats
    int* dotp = (int*)(wpart + 4096);            // 4*8*1024 ints

    k1<<<1024, 256, 0, stream>>>(hs, W, wpart, dotp);
    k2<<<(BATCH * HDIM) / 256, 256, 0, stream>>>(dotp, wpart, bias, alpha, out);
}